// Round 4
// baseline (3626.788 us; speedup 1.0000x reference)
//
#include <hip/hip_runtime.h>
#include <math.h>

#define S 512
#define W 64
#define MODES 16
#define PAIRS 130816  // 512*511/2
#define INV_SQRT_N 0.04419417382415922f  // 1/sqrt(512)
#define TWO_PI_OVER_N 0.012271846303085130f  // 2*pi/512
#define NB 512  // grid blocks; all co-resident (2/CU via launch_bounds)

// Hand-rolled grid barrier: sense-reversing generation counter, device scope.
// bar[0]=arrive count, bar[1]=generation. Zeroed by hipMemsetAsync pre-launch.
__device__ __forceinline__ void gridbar(unsigned* bar) {
    __syncthreads();
    if (threadIdx.x == 0) {
        __threadfence();  // release: publish this block's writes device-wide
        unsigned g = __hip_atomic_load(&bar[1], __ATOMIC_RELAXED, __HIP_MEMORY_SCOPE_AGENT);
        unsigned a = __hip_atomic_fetch_add(&bar[0], 1u, __ATOMIC_ACQ_REL, __HIP_MEMORY_SCOPE_AGENT);
        if (a == (unsigned)(NB - 1)) {
            __hip_atomic_store(&bar[0], 0u, __ATOMIC_RELAXED, __HIP_MEMORY_SCOPE_AGENT);
            __hip_atomic_store(&bar[1], g + 1u, __ATOMIC_RELEASE, __HIP_MEMORY_SCOPE_AGENT);
        } else {
            while (__hip_atomic_load(&bar[1], __ATOMIC_ACQUIRE, __HIP_MEMORY_SCOPE_AGENT) == g)
                __builtin_amdgcn_s_sleep(1);
        }
        __threadfence();  // acquire: see other blocks' writes
    }
    __syncthreads();
}

__global__ __launch_bounds__(256, 2) void k_fused(
    const float* __restrict__ x, const float* __restrict__ vecs,
    const float* __restrict__ fc0w, const float* __restrict__ fc0b,
    const float* __restrict__ specw, const float* __restrict__ convw,
    const float* __restrict__ convb, const float* __restrict__ fc1w,
    const float* __restrict__ fc1b, const float* __restrict__ fc2w,
    const float* __restrict__ fc2b, float* __restrict__ out,
    unsigned* __restrict__ bar, unsigned* __restrict__ vmaxu,
    float* __restrict__ h_std, float* __restrict__ hT,
    float* __restrict__ aT, float* __restrict__ pT,
    float* __restrict__ Xf, float* __restrict__ Yb,
    float* __restrict__ vr, float* __restrict__ uxm) {
    __shared__ float smem[8448];  // 33 KB pool, carved per stage
    int blk = blockIdx.x, tid = threadIdx.x;
    int lane = tid & 63, wv = tid >> 6;

    // ---------- stage fc0 (blocks 0..127): h[b,c,t]
    if (blk < 128) {
        int b = blk >> 6, c = blk & 63;
        float w0 = fc0w[c], w1 = fc0w[64 + c], bb = fc0b[c];
        for (int t = tid; t < S; t += 256) {
            float x0 = x[(b * S + t) * 2];
            float x1 = x[(b * S + t) * 2 + 1];
            h_std[(b * W + c) * S + t] = x0 * w0 + x1 * w1 + bb;
        }
    }
    gridbar(bar);

    for (int l = 0; l < 4; ++l) {
        // ---------- stage A: fft (0..127) || conv (128..191) || vmax zero (192)
        if (blk < 128) {
            int b = blk >> 6, ch = blk & 63;
            const float* hp = h_std + (b * W + ch) * S;
            float v0 = hp[tid], v1 = hp[tid + 256];
            float re[MODES], im[MODES];
#pragma unroll
            for (int m = 0; m < MODES; ++m) {
                float sn, cs;
                sincosf(TWO_PI_OVER_N * (float)(m * tid), &sn, &cs);
                float a = (m & 1) ? (v0 - v1) : (v0 + v1);
                re[m] = a * cs;
                im[m] = -a * sn;
            }
            float* part = smem;  // [4][32]
#pragma unroll
            for (int m = 0; m < MODES; ++m) {
                float r = re[m], ii = im[m];
                for (int off = 32; off; off >>= 1) {
                    r += __shfl_down(r, off);
                    ii += __shfl_down(ii, off);
                }
                if (lane == 0) { part[wv * 32 + 2 * m] = r; part[wv * 32 + 2 * m + 1] = ii; }
            }
            __syncthreads();
            if (tid < 32) {
                float s = part[tid] + part[32 + tid] + part[64 + tid] + part[96 + tid];
                Xf[(b * W + ch) * 32 + tid] = s * INV_SQRT_N;
            }
        } else if (blk < 192) {
            int cb = blk - 128;
            int b = cb >> 5, t0 = (cb & 31) * 16;
            int o = lane, tg = wv;
            float* hs = smem;            // 64*17
            float* wsh = smem + 1088;    // 64*65
            for (int idx = tid; idx < 1024; idx += 256) {
                int r = idx >> 4, t = idx & 15;
                hs[r * 17 + t] = h_std[(b * W + r) * S + t0 + t];
            }
            for (int idx = tid; idx < 4096; idx += 256)
                wsh[(idx >> 6) * 65 + (idx & 63)] = convw[l * 4096 + idx];
            __syncthreads();
            float wreg[64];
#pragma unroll
            for (int i = 0; i < W; ++i) wreg[i] = wsh[o * 65 + i];
            float bias = convb[l * W + o];
            for (int tt = 0; tt < 4; ++tt) {
                int tl = tg * 4 + tt;
                float acc = bias;
#pragma unroll
                for (int i = 0; i < W; ++i) acc = fmaf(wreg[i], hs[i * 17 + tl], acc);
                pT[(b * S + t0 + tl) * W + o] = acc;
            }
        } else if (blk == 192 && tid < 2) {
            __hip_atomic_store(&vmaxu[tid], 0u, __ATOMIC_RELAXED, __HIP_MEMORY_SCOPE_AGENT);
        }
        gridbar(bar);

        // ---------- stage B: mix (0..127): Y[b,o,m] = sum_i Xf[b,i,m]*wm[i,o,m]
        if (blk < 128) {
            int b = blk >> 6, o = blk & 63;
            int m = tid & 15, ip = tid >> 4;
            float* Xs = smem;              // 2048
            float* redr = smem + 2048;     // 16*17
            float* redi = smem + 2320;     // 16*17
            for (int idx = tid; idx < 2048; idx += 256) Xs[idx] = Xf[b * 2048 + idx];
            __syncthreads();
            float ar = 0.f, ai = 0.f;
#pragma unroll
            for (int q = 0; q < 4; ++q) {
                int i = ip * 4 + q;
                const float* wp = specw + (size_t)(((l * W + i) * W + o) * MODES + m) * 2;
                float wr = wp[0], wi = wp[1];
                float xr = Xs[i * 32 + 2 * m], xi = Xs[i * 32 + 2 * m + 1];
                ar += xr * wr - xi * wi;
                ai += xr * wi + xi * wr;
            }
            redr[ip * 17 + m] = ar; redi[ip * 17 + m] = ai;
            __syncthreads();
            if (tid < 16) {
                float sr = 0.f, si = 0.f;
                for (int p = 0; p < 16; ++p) { sr += redr[p * 17 + tid]; si += redi[p * 17 + tid]; }
                Yb[(b * W + o) * 32 + 2 * tid] = sr;
                Yb[(b * W + o) * 32 + 2 * tid + 1] = si;
            }
        }
        gridbar(bar);

        // ---------- stage C: irfft (0..127) -> aT[b,t,o]
        if (blk < 128) {
            int b = blk >> 6, t0 = (blk & 63) * 8;
            int o = lane, tg = wv;  // t = t0 + tg + 4*tt, tt in 0..1
            float* Ys = smem;  // 2048
            for (int idx = tid; idx < 2048; idx += 256) Ys[idx] = Yb[b * 2048 + idx];
            __syncthreads();
            float yr[MODES], yi[MODES];
#pragma unroll
            for (int m = 0; m < MODES; ++m) {
                yr[m] = Ys[o * 32 + 2 * m];
                yi[m] = Ys[o * 32 + 2 * m + 1];
            }
            float cc[MODES], ss[MODES], cd[MODES], sd[MODES];
#pragma unroll
            for (int m = 1; m < MODES; ++m) {
                sincosf(TWO_PI_OVER_N * (float)(m * (t0 + tg)), &ss[m], &cc[m]);
                sincosf(TWO_PI_OVER_N * (float)(4 * m), &sd[m], &cd[m]);
            }
            for (int tt = 0; tt < 2; ++tt) {
                int t = t0 + tg + 4 * tt;
                float acc = yr[0];
#pragma unroll
                for (int m = 1; m < MODES; ++m) {
                    acc += 2.0f * (yr[m] * cc[m] - yi[m] * ss[m]);
                    float nc = cc[m] * cd[m] - ss[m] * sd[m];
                    float ns = ss[m] * cd[m] + cc[m] * sd[m];
                    cc[m] = nc; ss[m] = ns;
                }
                aT[(b * S + t) * W + o] = acc * INV_SQRT_N;
            }
        }
        gridbar(bar);

        // ---------- stage D: pair (all 512 blocks)
        {
            int b = blk >> 8;
            int rest = blk & 255;
            int i0 = (rest & 15) * 32, j0 = (rest >> 4) * 32;
            int tx = tid & 15, ty = tid >> 4;
            float* Pi = smem;           // 64*33
            float* Pj = smem + 2112;
            float* Vi = smem + 4224;
            float* Vj = smem + 6336;
            for (int idx = tid; idx < 2048; idx += 256) {
                int k = idx >> 6, c = idx & 63;
                Pi[c * 33 + k] = pT[(b * S + i0 + k) * W + c];
                Pj[c * 33 + k] = pT[(b * S + j0 + k) * W + c];
                Vi[c * 33 + k] = aT[(b * S + i0 + k) * W + c];
                Vj[c * 33 + k] = aT[(b * S + j0 + k) * W + c];
            }
            __syncthreads();
            float ax[2][2] = {{0.f, 0.f}, {0.f, 0.f}};
            float av[2][2] = {{0.f, 0.f}, {0.f, 0.f}};
            for (int c = 0; c < W; ++c) {
                float pi0 = Pi[c * 33 + 2 * tx], pi1 = Pi[c * 33 + 2 * tx + 1];
                float pj0 = Pj[c * 33 + 2 * ty], pj1 = Pj[c * 33 + 2 * ty + 1];
                float vi0 = Vi[c * 33 + 2 * tx], vi1 = Vi[c * 33 + 2 * tx + 1];
                float vj0 = Vj[c * 33 + 2 * ty], vj1 = Vj[c * 33 + 2 * ty + 1];
                float d;
                d = pi0 - pj0; ax[0][0] = fmaf(d, d, ax[0][0]);
                d = pi1 - pj0; ax[1][0] = fmaf(d, d, ax[1][0]);
                d = pi0 - pj1; ax[0][1] = fmaf(d, d, ax[0][1]);
                d = pi1 - pj1; ax[1][1] = fmaf(d, d, ax[1][1]);
                d = vi0 - vj0; av[0][0] = fmaf(d, d, av[0][0]);
                d = vi1 - vj0; av[1][0] = fmaf(d, d, av[1][0]);
                d = vi0 - vj1; av[0][1] = fmaf(d, d, av[0][1]);
                d = vi1 - vj1; av[1][1] = fmaf(d, d, av[1][1]);
            }
            float mx = 0.f;
#pragma unroll
            for (int jj = 0; jj < 2; ++jj) {
#pragma unroll
                for (int ii = 0; ii < 2; ++ii) {
                    int i = i0 + 2 * tx + ii, j = j0 + 2 * ty + jj;
                    float xr = sqrtf(ax[ii][jj]);
                    float vv = sqrtf(av[ii][jj]);
                    vr[((size_t)b * S + j) * S + i] = vv;
                    uxm[((size_t)b * S + j) * S + i] = expf(-xr);
                    mx = fmaxf(mx, vv);
                }
            }
            for (int off = 32; off; off >>= 1) mx = fmaxf(mx, __shfl_xor(mx, off));
            if (lane == 0) atomicMax(&vmaxu[b], __float_as_uint(mx));
        }
        gridbar(bar);

        // ---------- stage E: dsmc (all blocks, 2 rows each)
        {
            int b = blk >> 8, jb = blk & 255;
            float* vrow = smem;                  // 512
            float* urow = smem + 512;            // 512
            float* wl = smem + 1024;             // 512
            int* idxl = (int*)(smem + 1536);     // 512
            int* pl = (int*)(smem + 2048);       // 512
            int* wcnt = (int*)(smem + 2560);     // 4
            float* SVp = smem + 2576;            // 4*64
            float* SXp = smem + 2832;            // 4*64
            float* Tsh = smem + 3088;            // 64
            for (int q = 0; q < 2; ++q) {
                int j = jb + 256 * q;
                __syncthreads();
                const float* vrp = vr + ((size_t)b * S + j) * S;
                const float* uxp = uxm + ((size_t)b * S + j) * S;
                for (int i = tid; i < S; i += 256) { vrow[i] = vrp[i]; urow[i] = uxp[i]; }
                __syncthreads();
                float vmax = __uint_as_float(
                    __hip_atomic_load(&vmaxu[b], __ATOMIC_RELAXED, __HIP_MEMORY_SCOPE_AGENT));
                int i1 = wv * 128 + lane, i2 = i1 + 64;
                bool a1 = (vrow[i1] / vmax) * urow[i1] > 0.1f;
                bool a2 = (vrow[i2] / vmax) * urow[i2] > 0.1f;
                unsigned long long m1 = __ballot(a1), m2 = __ballot(a2);
                int c1 = (int)__popcll(m1), c2 = (int)__popcll(m2);
                if (lane == 0) wcnt[wv] = c1 + c2;
                __syncthreads();
                int off = 0;
                for (int w = 0; w < wv; ++w) off += wcnt[w];
                int A = wcnt[0] + wcnt[1] + wcnt[2] + wcnt[3];
                unsigned long long bel = (1ull << lane) - 1ull;
                if (a1) {
                    int pos = off + (int)__popcll(m1 & bel);
                    int i = i1;
                    idxl[pos] = i;
                    wl[pos] = ((i < j) ? 1.0f : -1.0f) * vrow[i];
                    int lo = (i < j) ? i : j, hi = (i < j) ? j : i;
                    pl[pos] = lo * 511 - ((lo * (lo - 1)) >> 1) + (hi - lo - 1);
                }
                if (a2) {
                    int pos = off + c1 + (int)__popcll(m2 & bel);
                    int i = i2;
                    idxl[pos] = i;
                    wl[pos] = ((i < j) ? 1.0f : -1.0f) * vrow[i];
                    int lo = (i < j) ? i : j, hi = (i < j) ? j : i;
                    pl[pos] = lo * 511 - ((lo * (lo - 1)) >> 1) + (hi - lo - 1);
                }
                __syncthreads();
                // partner channel sums, lanes over channels (coalesced)
                float sv = 0.f, sx = 0.f;
                for (int k = wv; k < A; k += 4) {
                    int i = idxl[k];
                    sv += aT[((size_t)b * S + i) * W + lane];
                    sx += pT[((size_t)b * S + i) * W + lane];
                }
                SVp[wv * 64 + lane] = sv;
                SXp[wv * 64 + lane] = sx;
                // projection: T[c] = sum_k wl[k] * R[c, pl[k]], lanes over pair list
                const float* Rb = vecs + (size_t)((l * 2 + b) * W) * PAIRS;
                for (int cc = 0; cc < 16; ++cc) {
                    int c = wv * 16 + cc;
                    const float* Rc = Rb + (size_t)c * PAIRS;
                    float t = 0.f;
                    for (int k = lane; k < A; k += 64) t += wl[k] * Rc[pl[k]];
                    for (int o2 = 32; o2; o2 >>= 1) t += __shfl_down(t, o2);
                    if (lane == 0) Tsh[c] = t;
                }
                __syncthreads();
                if (tid < 64) {
                    int c = tid;
                    float svt = SVp[c] + SVp[64 + c] + SVp[128 + c] + SVp[192 + c];
                    float sxt = SXp[c] + SXp[64 + c] + SXp[128 + c] + SXp[192 + c];
                    float vj = aT[((size_t)b * S + j) * W + c];
                    float xj = pT[((size_t)b * S + j) * W + c];
                    float vnew = vj + 0.5f * ((float)A * vj - svt) + Tsh[c];
                    float accx = 0.5f * ((float)A * xj + sxt);
                    float xnew = (xj + accx) / (float)(A + 1) + vnew;
                    if (l < 3) xnew = fmaxf(xnew, 0.0f);
                    hT[((size_t)b * S + j) * W + c] = xnew;
                    h_std[((size_t)b * W + c) * S + j] = xnew;
                }
            }
        }
        gridbar(bar);
    }

    // ---------- head (all blocks, 2 t each)
    {
        int b = blk >> 8, tb = blk & 255;
        int q = tid >> 7, k2 = tid & 127;
        int t = tb * 2 + q;
        float* hsh = smem;        // [2][64]
        float* red = smem + 128;  // [4]
        if (k2 < 64) hsh[q * 64 + k2] = hT[((size_t)b * S + t) * W + k2];
        __syncthreads();
        float acc = fc1b[k2];
#pragma unroll
        for (int c = 0; c < W; ++c) acc = fmaf(hsh[q * 64 + c], fc1w[c * 128 + k2], acc);
        acc = fmaxf(acc, 0.f);
        float p = acc * fc2w[k2];
        for (int off = 32; off; off >>= 1) p += __shfl_down(p, off);
        if (lane == 0) red[wv] = p;
        __syncthreads();
        if (tid == 0) out[b * S + tb * 2] = red[0] + red[1] + fc2b[0];
        if (tid == 128) out[b * S + tb * 2 + 1] = red[2] + red[3] + fc2b[0];
    }
}

extern "C" void kernel_launch(void* const* d_in, const int* in_sizes, int n_in,
                              void* d_out, int out_size, void* d_ws, size_t ws_size,
                              hipStream_t stream) {
    const float* x = (const float*)d_in[0];
    const float* vecs = (const float*)d_in[2];
    const float* fc0w = (const float*)d_in[3];
    const float* fc0b = (const float*)d_in[4];
    const float* specw = (const float*)d_in[5];
    const float* convw = (const float*)d_in[6];
    const float* convb = (const float*)d_in[7];
    const float* fc1w = (const float*)d_in[8];
    const float* fc1b = (const float*)d_in[9];
    const float* fc2w = (const float*)d_in[10];
    const float* fc2b = (const float*)d_in[11];
    float* out = (float*)d_out;

    char* ws = (char*)d_ws;
    unsigned* bar = (unsigned*)ws;                    // 2 u32 barrier state
    unsigned* vmax = (unsigned*)(ws + 64);            // 2 u32 (float bits)
    float* h_std = (float*)(ws + 256);                // 2*64*512
    float* hT = h_std + 65536;
    float* aT = hT + 65536;
    float* pT = aT + 65536;
    float* Xf = pT + 65536;                           // 2*64*32
    float* Yb = Xf + 4096;
    float* vrbuf = Yb + 4096;                         // 2*512*512
    float* uxbuf = vrbuf + 524288;

    hipMemsetAsync(d_ws, 0, 256, stream);  // zero barrier state (+vmax)
    k_fused<<<NB, 256, 0, stream>>>(x, vecs, fc0w, fc0b, specw, convw, convb,
                                    fc1w, fc1b, fc2w, fc2b, out, bar, vmax,
                                    h_std, hT, aT, pT, Xf, Yb, vrbuf, uxbuf);
}

// Round 5
// 767.614 us; speedup vs baseline: 4.7248x; 4.7248x over previous
//
#include <hip/hip_runtime.h>
#include <math.h>

#define S 512
#define W 64
#define MODES 16
#define PAIRS 130816  // 512*511/2
#define INV_SQRT_N 0.04419417382415922f  // 1/sqrt(512)
#define TWO_PI_OVER_N 0.012271846303085130f  // 2*pi/512

// ---------------- fc0: h[b,c,t] = x[b,t,0]*w[0,c] + x[b,t,1]*w[1,c] + bias[c]
__global__ __launch_bounds__(256) void k_fc0(const float* __restrict__ x,
                                             const float* __restrict__ w,
                                             const float* __restrict__ bias,
                                             float* __restrict__ h) {
    int b = blockIdx.x >> 6, c = blockIdx.x & 63;
    int tid = threadIdx.x;
    float w0 = w[c], w1 = w[64 + c], bb = bias[c];
    for (int t = tid; t < S; t += 256) {
        float x0 = x[(b * S + t) * 2];
        float x1 = x[(b * S + t) * 2 + 1];
        h[(b * W + c) * S + t] = x0 * w0 + x1 * w1 + bb;
    }
}

// ---------------- rfft (ortho), first 16 modes only. block=(b,c), 256 thr.
__global__ __launch_bounds__(256) void k_fft(const float* __restrict__ h,
                                             float* __restrict__ Xf) {
    int b = blockIdx.x >> 6, ch = blockIdx.x & 63;
    int tid = threadIdx.x;  // t = tid and tid+256
    const float* hp = h + (b * W + ch) * S;
    float v0 = hp[tid], v1 = hp[tid + 256];
    float re[MODES], im[MODES];
#pragma unroll
    for (int m = 0; m < MODES; ++m) {
        float sn, cs;
        sincosf(TWO_PI_OVER_N * (float)(m * tid), &sn, &cs);
        float a = (m & 1) ? (v0 - v1) : (v0 + v1);  // e^{-i pi m} = (-1)^m
        re[m] = a * cs;
        im[m] = -a * sn;
    }
    __shared__ float part[4][32];
    int lane = tid & 63, wv = tid >> 6;
#pragma unroll
    for (int m = 0; m < MODES; ++m) {
        float r = re[m], ii = im[m];
        for (int off = 32; off; off >>= 1) {
            r += __shfl_down(r, off);
            ii += __shfl_down(ii, off);
        }
        if (lane == 0) { part[wv][2 * m] = r; part[wv][2 * m + 1] = ii; }
    }
    __syncthreads();
    if (tid < 32) {
        float s = part[0][tid] + part[1][tid] + part[2][tid] + part[3][tid];
        Xf[(b * W + ch) * 32 + tid] = s * INV_SQRT_N;
    }
}

// ---------------- complex channel mix: Y[b,o,m] = sum_i Xf[b,i,m]*wm[i,o,m]
__global__ __launch_bounds__(256) void k_mix(const float* __restrict__ Xf,
                                             const float* __restrict__ specw,
                                             float* __restrict__ Y, int l) {
    int b = blockIdx.x >> 6, o = blockIdx.x & 63;
    int tid = threadIdx.x, m = tid & 15, ip = tid >> 4;
    __shared__ float Xs[2048];
    for (int idx = tid; idx < 2048; idx += 256) Xs[idx] = Xf[b * 2048 + idx];
    __syncthreads();
    float ar = 0.f, ai = 0.f;
#pragma unroll
    for (int q = 0; q < 4; ++q) {
        int i = ip * 4 + q;
        const float* wp = specw + (size_t)(((l * W + i) * W + o) * MODES + m) * 2;
        float wr = wp[0], wi = wp[1];
        float xr = Xs[i * 32 + 2 * m], xi = Xs[i * 32 + 2 * m + 1];
        ar += xr * wr - xi * wi;
        ai += xr * wi + xi * wr;
    }
    __shared__ float redr[16][17], redi[16][17];
    redr[ip][m] = ar; redi[ip][m] = ai;
    __syncthreads();
    if (tid < 16) {
        float sr = 0.f, si = 0.f;
        for (int p = 0; p < 16; ++p) { sr += redr[p][tid]; si += redi[p][tid]; }
        Y[(b * W + o) * 32 + 2 * tid] = sr;
        Y[(b * W + o) * 32 + 2 * tid + 1] = si;
    }
}

// ---------------- irfft (ortho, 16 modes) -> aT[b,t,o]
__global__ __launch_bounds__(256) void k_irfft(const float* __restrict__ Y,
                                               float* __restrict__ aT) {
    int blk = blockIdx.x;
    int b = blk >> 4, t0 = (blk & 15) * 32;
    int tid = threadIdx.x;
    int o = tid & 63, tg = tid >> 6;  // t = t0 + tg + 4*tt, tt in 0..7
    __shared__ float Ys[2048];
    for (int idx = tid; idx < 2048; idx += 256) Ys[idx] = Y[b * 2048 + idx];
    __syncthreads();
    float yr[MODES], yi[MODES];
#pragma unroll
    for (int m = 0; m < MODES; ++m) {
        yr[m] = Ys[o * 32 + 2 * m];
        yi[m] = Ys[o * 32 + 2 * m + 1];
    }
    float cc[MODES], ss[MODES], cd[MODES], sd[MODES];
#pragma unroll
    for (int m = 1; m < MODES; ++m) {
        sincosf(TWO_PI_OVER_N * (float)(m * (t0 + tg)), &ss[m], &cc[m]);
        sincosf(TWO_PI_OVER_N * (float)(4 * m), &sd[m], &cd[m]);
    }
    for (int tt = 0; tt < 8; ++tt) {
        int t = t0 + tg + 4 * tt;
        float acc = yr[0];
#pragma unroll
        for (int m = 1; m < MODES; ++m) {
            acc += 2.0f * (yr[m] * cc[m] - yi[m] * ss[m]);
            float nc = cc[m] * cd[m] - ss[m] * sd[m];
            float ns = ss[m] * cd[m] + cc[m] * sd[m];
            cc[m] = nc; ss[m] = ns;
        }
        aT[(b * S + t) * W + o] = acc * INV_SQRT_N;
    }
}

// ---------------- pointwise conv: pT[b,t,o] = sum_i w[o,i]*h[b,i,t] + bias[o]
__global__ __launch_bounds__(256) void k_conv(const float* __restrict__ h,
                                              const float* __restrict__ convw,
                                              const float* __restrict__ convb,
                                              float* __restrict__ pT,
                                              unsigned* __restrict__ vmax, int l) {
    int blk = blockIdx.x;
    int b = blk >> 4, t0 = (blk & 15) * 32;
    int tid = threadIdx.x;
    int o = tid & 63, tg = tid >> 6;
    if (blk == 0 && tid < 2) vmax[tid] = 0u;  // zero v_r_max for this layer
    __shared__ float hs[64 * 33];
    __shared__ float wsh[64 * 65];
    for (int idx = tid; idx < 2048; idx += 256) {
        int r = idx >> 5, t = idx & 31;
        hs[r * 33 + t] = h[(b * W + r) * S + t0 + t];
    }
    for (int idx = tid; idx < 4096; idx += 256) {
        wsh[(idx >> 6) * 65 + (idx & 63)] = convw[l * 4096 + idx];
    }
    __syncthreads();
    float wreg[64];
#pragma unroll
    for (int i = 0; i < W; ++i) wreg[i] = wsh[o * 65 + i];
    float bias = convb[l * W + o];
    for (int tt = 0; tt < 8; ++tt) {
        int tl = tg * 8 + tt;
        float acc = bias;
#pragma unroll
        for (int i = 0; i < W; ++i) acc = fmaf(wreg[i], hs[i * 33 + tl], acc);
        pT[(b * S + t0 + tl) * W + o] = acc;
    }
}

// ---------------- pairwise: v_r[b,j,i], u_x[b,j,i]=exp(-x_r), atomicMax v_r_max
__global__ __launch_bounds__(256) void k_pair(const float* __restrict__ pT,
                                              const float* __restrict__ aT,
                                              float* __restrict__ vr,
                                              float* __restrict__ uxm,
                                              unsigned* __restrict__ vmax) {
    int blk = blockIdx.x;
    int b = blk >> 8;
    int rest = blk & 255;
    int i0 = (rest & 15) * 32, j0 = (rest >> 4) * 32;
    int tid = threadIdx.x;
    int tx = tid & 15, ty = tid >> 4;
    __shared__ float Pi[64 * 33], Pj[64 * 33], Vi[64 * 33], Vj[64 * 33];
    for (int idx = tid; idx < 2048; idx += 256) {
        int k = idx >> 6, c = idx & 63;
        Pi[c * 33 + k] = pT[(b * S + i0 + k) * W + c];
        Pj[c * 33 + k] = pT[(b * S + j0 + k) * W + c];
        Vi[c * 33 + k] = aT[(b * S + i0 + k) * W + c];
        Vj[c * 33 + k] = aT[(b * S + j0 + k) * W + c];
    }
    __syncthreads();
    float ax[2][2] = {{0.f, 0.f}, {0.f, 0.f}};
    float av[2][2] = {{0.f, 0.f}, {0.f, 0.f}};
    for (int c = 0; c < W; ++c) {
        float pi0 = Pi[c * 33 + 2 * tx], pi1 = Pi[c * 33 + 2 * tx + 1];
        float pj0 = Pj[c * 33 + 2 * ty], pj1 = Pj[c * 33 + 2 * ty + 1];
        float vi0 = Vi[c * 33 + 2 * tx], vi1 = Vi[c * 33 + 2 * tx + 1];
        float vj0 = Vj[c * 33 + 2 * ty], vj1 = Vj[c * 33 + 2 * ty + 1];
        float d;
        d = pi0 - pj0; ax[0][0] = fmaf(d, d, ax[0][0]);
        d = pi1 - pj0; ax[1][0] = fmaf(d, d, ax[1][0]);
        d = pi0 - pj1; ax[0][1] = fmaf(d, d, ax[0][1]);
        d = pi1 - pj1; ax[1][1] = fmaf(d, d, ax[1][1]);
        d = vi0 - vj0; av[0][0] = fmaf(d, d, av[0][0]);
        d = vi1 - vj0; av[1][0] = fmaf(d, d, av[1][0]);
        d = vi0 - vj1; av[0][1] = fmaf(d, d, av[0][1]);
        d = vi1 - vj1; av[1][1] = fmaf(d, d, av[1][1]);
    }
    float mx = 0.f;
#pragma unroll
    for (int jj = 0; jj < 2; ++jj) {
#pragma unroll
        for (int ii = 0; ii < 2; ++ii) {
            int i = i0 + 2 * tx + ii, j = j0 + 2 * ty + jj;
            float xr = sqrtf(ax[ii][jj]);
            float vv = sqrtf(av[ii][jj]);
            vr[((size_t)b * S + j) * S + i] = vv;
            uxm[((size_t)b * S + j) * S + i] = expf(-xr);
            mx = fmaxf(mx, vv);
        }
    }
    for (int off = 32; off; off >>= 1) mx = fmaxf(mx, __shfl_xor(mx, off));
    if ((tid & 63) == 0) atomicMax(&vmax[b], __float_as_uint(mx));
}

// ---------------- mask: per row j -> wpair (contiguous upper segment), A, partner sums, Tg=0
__global__ __launch_bounds__(256) void k_mask(const float* __restrict__ vr,
                                              const float* __restrict__ uxm,
                                              const unsigned* __restrict__ vmaxu,
                                              const float* __restrict__ aT,
                                              const float* __restrict__ pT,
                                              float* __restrict__ wpair,
                                              float* __restrict__ sv,
                                              float* __restrict__ sx,
                                              int* __restrict__ Acnt,
                                              float* __restrict__ Tg) {
    int b = blockIdx.x >> 9, j = blockIdx.x & 511;
    int tid = threadIdx.x, lane = tid & 63, wv = tid >> 6;
    __shared__ float wrow[S];
    __shared__ float SV[4][64], SX[4][64];
    __shared__ int cnt4[4];
    const float* vrp = vr + ((size_t)b * S + j) * S;
    const float* uxp = uxm + ((size_t)b * S + j) * S;
    float vmax = __uint_as_float(vmaxu[b]);
    int mycnt = 0;
    for (int i = tid; i < S; i += 256) {
        float v = vrp[i], u = uxp[i];
        bool act = (v / vmax) * u > 0.1f;
        wrow[i] = act ? v : 0.f;
        mycnt += act ? 1 : 0;
    }
    for (int o = 32; o; o >>= 1) mycnt += __shfl_down(mycnt, o);
    if (lane == 0) cnt4[wv] = mycnt;
    __syncthreads();
    int A = cnt4[0] + cnt4[1] + cnt4[2] + cnt4[3];
    if (tid == 0) Acnt[b * S + j] = A;
    if (tid < 64) Tg[((size_t)b * S + j) * W + tid] = 0.f;
    size_t tri = (size_t)j * 511 - (((size_t)j * (j - 1)) >> 1);
    for (int i = j + 1 + tid; i < S; i += 256)
        wpair[(size_t)b * PAIRS + tri + (i - j - 1)] = wrow[i];
    // partner sums: lanes over channels (coalesced, L2-resident)
    float svp = 0.f, sxp = 0.f;
    const float* aTb = aT + (size_t)b * S * W;
    const float* pTb = pT + (size_t)b * S * W;
    for (int k = 0; k < 128; ++k) {
        int i = wv * 128 + k;
        float w01 = (wrow[i] != 0.f) ? 1.0f : 0.0f;
        svp = fmaf(w01, aTb[i * W + lane], svp);
        sxp = fmaf(w01, pTb[i * W + lane], sxp);
    }
    SV[wv][lane] = svp; SX[wv][lane] = sxp;
    __syncthreads();
    if (tid < 64) {
        sv[((size_t)b * S + j) * W + tid] = SV[0][tid] + SV[1][tid] + SV[2][tid] + SV[3][tid];
        sx[((size_t)b * S + j) * W + tid] = SX[0][tid] + SX[1][tid] + SX[2][tid] + SX[3][tid];
    }
}

// ---------------- proj: single coalesced sweep of R, both signs.
// grid (36 upper 64x64 tiles, 8 channel groups, 2 b), 256 thr.
__global__ __launch_bounds__(256) void k_proj2(const float* __restrict__ wpair,
                                               const float* __restrict__ vecs,
                                               float* __restrict__ Tg, int l) {
    int tile = blockIdx.x, cg = blockIdx.y, b = blockIdx.z;
    int ti = 0, rem = tile;
    while (rem >= 8 - ti) { rem -= 8 - ti; ++ti; }
    int tj = ti + rem;
    int i0 = ti * 64, j0 = tj * 64;
    int tid = threadIdx.x, lane = tid & 63, wv = tid >> 6;
    __shared__ float Tjs[4][64][9];
    __shared__ float Tis[64][9];
    for (int k2 = tid; k2 < 4 * 64 * 9; k2 += 256) ((float*)Tjs)[k2] = 0.f;
    for (int k2 = tid; k2 < 64 * 9; k2 += 256) ((float*)Tis)[k2] = 0.f;
    __syncthreads();
    const float* wb = wpair + (size_t)b * PAIRS;
    const float* Rb = vecs + (size_t)((l * 2 + b) * W + cg * 8) * PAIRS;
    float accj[8] = {0.f, 0.f, 0.f, 0.f, 0.f, 0.f, 0.f, 0.f};
    int gj = j0 + lane;
    for (int s = 0; s < 16; ++s) {
        int li = wv + 4 * s;
        int gi = i0 + li;
        int pbase = gi * 511 - ((gi * (gi - 1)) >> 1) + (j0 - gi - 1);
        bool valid = gj > gi;
        int idx = valid ? (pbase + lane) : 0;
        float w = wb[idx];
        if (!valid) w = 0.f;
        if (__ballot(w != 0.f) == 0ull) continue;
        float part[8];
#pragma unroll
        for (int cc = 0; cc < 8; ++cc) {
            float r = Rb[(size_t)cc * PAIRS + idx];
            float p = w * r;
            accj[cc] += p;
            part[cc] = p;
        }
#pragma unroll
        for (int cc = 0; cc < 8; ++cc) {
            float p = part[cc];
            for (int o = 32; o; o >>= 1) p += __shfl_xor(p, o);
            if (lane == 0) Tis[li][cc] = p;
        }
    }
#pragma unroll
    for (int cc = 0; cc < 8; ++cc) Tjs[wv][lane][cc] = accj[cc];
    __syncthreads();
    for (int k2 = tid; k2 < 512; k2 += 256) {
        int r = k2 >> 3, cc = k2 & 7;
        float sj = Tjs[0][r][cc] + Tjs[1][r][cc] + Tjs[2][r][cc] + Tjs[3][r][cc];
        if (sj != 0.f)
            atomicAdd(&Tg[((size_t)b * S + j0 + r) * W + cg * 8 + cc], sj);
        float si = Tis[r][cc];
        if (si != 0.f)
            atomicAdd(&Tg[((size_t)b * S + i0 + r) * W + cg * 8 + cc], -si);
    }
}

// ---------------- finalize: vnew/xnew per (b,j,c)
__global__ __launch_bounds__(256) void k_fin(const float* __restrict__ aT,
                                             const float* __restrict__ pT,
                                             const float* __restrict__ sv,
                                             const float* __restrict__ sx,
                                             const int* __restrict__ Acnt,
                                             const float* __restrict__ Tg,
                                             float* __restrict__ h_std,
                                             float* __restrict__ hT,
                                             int do_relu) {
    int g = blockIdx.x * 4 + (threadIdx.x >> 6);  // global row 0..1023
    int b = g >> 9, j = g & 511;
    int c = threadIdx.x & 63;
    size_t row = ((size_t)b * S + j) * W;
    float A = (float)Acnt[b * S + j];
    float vj = aT[row + c], xj = pT[row + c];
    float vnew = vj + 0.5f * (A * vj - sv[row + c]) + Tg[row + c];
    float accx = 0.5f * (A * xj + sx[row + c]);
    float xnew = (xj + accx) / (A + 1.0f) + vnew;
    if (do_relu) xnew = fmaxf(xnew, 0.0f);
    hT[row + c] = xnew;
    h_std[((size_t)b * W + c) * S + j] = xnew;
}

// ---------------- head: out[b,t] = relu(hT[b,t,:]@fc1 + b1) @ fc2 + b2
__global__ __launch_bounds__(128) void k_head(const float* __restrict__ hT,
                                              const float* __restrict__ fc1w,
                                              const float* __restrict__ fc1b,
                                              const float* __restrict__ fc2w,
                                              const float* __restrict__ fc2b,
                                              float* __restrict__ out) {
    int blk = blockIdx.x;
    int b = blk >> 9, t = blk & 511;
    int k = threadIdx.x;  // 0..127
    __shared__ float hsh[64];
    __shared__ float red[2];
    if (k < 64) hsh[k] = hT[(b * S + t) * W + k];
    __syncthreads();
    float acc = fc1b[k];
#pragma unroll
    for (int c = 0; c < W; ++c) acc = fmaf(hsh[c], fc1w[c * 128 + k], acc);
    acc = fmaxf(acc, 0.f);
    float p = acc * fc2w[k];
    for (int off = 32; off; off >>= 1) p += __shfl_down(p, off);
    int lane = k & 63, wv = k >> 6;
    if (lane == 0) red[wv] = p;
    __syncthreads();
    if (k == 0) out[b * S + t] = red[0] + red[1] + fc2b[0];
}

extern "C" void kernel_launch(void* const* d_in, const int* in_sizes, int n_in,
                              void* d_out, int out_size, void* d_ws, size_t ws_size,
                              hipStream_t stream) {
    const float* x = (const float*)d_in[0];
    const float* vecs = (const float*)d_in[2];
    const float* fc0w = (const float*)d_in[3];
    const float* fc0b = (const float*)d_in[4];
    const float* specw = (const float*)d_in[5];
    const float* convw = (const float*)d_in[6];
    const float* convb = (const float*)d_in[7];
    const float* fc1w = (const float*)d_in[8];
    const float* fc1b = (const float*)d_in[9];
    const float* fc2w = (const float*)d_in[10];
    const float* fc2b = (const float*)d_in[11];
    float* out = (float*)d_out;

    char* ws = (char*)d_ws;
    unsigned* vmax = (unsigned*)ws;                   // 2 x u32 (float bits)
    float* h_std = (float*)(ws + 256);                // 2*64*512
    float* hT = h_std + 65536;
    float* aT = hT + 65536;
    float* pT = aT + 65536;
    float* Xf = pT + 65536;                           // 2*64*32
    float* Yb = Xf + 4096;
    float* vrbuf = Yb + 4096;                         // 2*512*512
    float* uxbuf = vrbuf + 524288;                    // 2*512*512
    float* Tg = uxbuf + 524288;                       // 2*512*64
    float* svb = Tg + 65536;                          // 2*512*64
    float* sxb = svb + 65536;                         // 2*512*64
    int* Acnt = (int*)(sxb + 65536);                  // 2*512
    float* wpair = (float*)(Acnt + 1024);             // 2*PAIRS

    k_fc0<<<128, 256, 0, stream>>>(x, fc0w, fc0b, h_std);
    for (int l = 0; l < 4; ++l) {
        k_fft<<<128, 256, 0, stream>>>(h_std, Xf);
        k_mix<<<128, 256, 0, stream>>>(Xf, specw, Yb, l);
        k_irfft<<<32, 256, 0, stream>>>(Yb, aT);
        k_conv<<<32, 256, 0, stream>>>(h_std, convw, convb, pT, vmax, l);
        k_pair<<<512, 256, 0, stream>>>(pT, aT, vrbuf, uxbuf, vmax);
        k_mask<<<1024, 256, 0, stream>>>(vrbuf, uxbuf, vmax, aT, pT,
                                         wpair, svb, sxb, Acnt, Tg);
        k_proj2<<<dim3(36, 8, 2), 256, 0, stream>>>(wpair, vecs, Tg, l);
        k_fin<<<256, 256, 0, stream>>>(aT, pT, svb, sxb, Acnt, Tg,
                                       h_std, hT, (l < 3) ? 1 : 0);
    }
    k_head<<<1024, 128, 0, stream>>>(hT, fc1w, fc1b, fc2w, fc2b, out);
}